// Round 1
// baseline (281.096 us; speedup 1.0000x reference)
//
#include <hip/hip_runtime.h>

// MonarchOutProjection: out[t][r*32+q] = sum_p R[q][r][p] * sum_m L[p][q][m] * x[t][m*32+p]
// Memory-bound (268 MB @ ~6.3 TB/s => ~43 us floor). MFMA bf16 16x16x32 for both stages.
// Block = 256 thr (4 waves) = 16 tokens. LDS: xs + y1s, 32 KiB each (bf16), XOR-swizzled
// columns (c ^ 2t) so fragment reads/writes spread over 16 banks. 2 blocks/CU.

typedef __attribute__((ext_vector_type(8))) short short8;
typedef __attribute__((ext_vector_type(4))) float floatx4;

__device__ __forceinline__ unsigned int f2bf(float f) {
    unsigned int u = __float_as_uint(f);
    return (u + 0x7fffu + ((u >> 16) & 1u)) >> 16;   // RNE f32->bf16 bits
}
__device__ __forceinline__ unsigned int pack2bf(float a, float b) {
    return f2bf(a) | (f2bf(b) << 16);
}
__device__ __forceinline__ float bf2f(unsigned int u16) {
    return __uint_as_float(u16 << 16);
}

__global__ __launch_bounds__(256, 2)
void monarch_kernel(const float* __restrict__ x,
                    const float* __restrict__ L,
                    const float* __restrict__ R,
                    float* __restrict__ out) {
    // Swizzled layouts: element (t, c) lives at xs[t][c ^ (2*t)] (XOR touches bits 1..4 only,
    // i.e. permutes within a 32-element group; all our accesses keep c's low 5 bits as the
    // varying part, so the XOR stays confined and pairs stay contiguous for u32 access).
    __shared__ __align__(16) unsigned short xs [16][1024];  // x tile, later reused as y2 tile
    __shared__ __align__(16) unsigned short y1s[16][1024];  // y1 tile, c = q*32 + p

    const int tid  = threadIdx.x;
    const int w    = tid >> 6;        // wave id 0..3
    const int lane = tid & 63;
    const int tl   = lane & 15;       // N-dim lane index (token t) / M-dim index (q or r)
    const int quad = lane >> 4;       // K-group (8 consecutive k per quad)
    const long tok0 = (long)blockIdx.x * 16;

    // ---------- stage in: x tile -> xs (bf16, swizzled), fully coalesced ----------
    {
        const int c = tid * 4;        // covers [0,1024) across 256 threads
        #pragma unroll
        for (int t = 0; t < 16; ++t) {
            const float4 v = *(const float4*)(x + (tok0 + t) * 1024 + c);
            *(unsigned int*)&xs[t][(c    ) ^ (2 * t)] = pack2bf(v.x, v.y);
            *(unsigned int*)&xs[t][(c + 2) ^ (2 * t)] = pack2bf(v.z, v.w);
        }
    }
    __syncthreads();

    // ---------- stage 1: per p: D[q][t] = L[p] (q x m) * X_p (m x t) ----------
    // A-frag (L): lane holds A[q = lane&15][k = quad*8+j], contiguous in m -> global float4.
    // B-frag (x): lane holds B[k = quad*8+j][t = lane&15] = xs[t][m*32+p], strided u16 reads.
    {
        const int xsw = 2 * tl;
        #pragma unroll
        for (int pp = 0; pp < 8; ++pp) {
            const int p  = w * 8 + pp;            // waves partition p
            const int pX = p ^ xsw;               // swizzled low-5 bits
            short8 b1;
            #pragma unroll
            for (int j = 0; j < 8; ++j)
                b1[j] = (short)xs[tl][quad * 256 + j * 32 + pX];
            #pragma unroll
            for (int qt = 0; qt < 2; ++qt) {
                const int q = qt * 16 + tl;
                const float* lp = L + ((p * 32 + q) * 32 + quad * 8);
                const float4 la = *(const float4*)lp;
                const float4 lb = *(const float4*)(lp + 4);
                short8 a1;
                a1[0] = (short)f2bf(la.x); a1[1] = (short)f2bf(la.y);
                a1[2] = (short)f2bf(la.z); a1[3] = (short)f2bf(la.w);
                a1[4] = (short)f2bf(lb.x); a1[5] = (short)f2bf(lb.y);
                a1[6] = (short)f2bf(lb.z); a1[7] = (short)f2bf(lb.w);
                floatx4 acc = {0.f, 0.f, 0.f, 0.f};
                acc = __builtin_amdgcn_mfma_f32_16x16x32_bf16(a1, b1, acc, 0, 0, 0);
                // D: col(lane&15) = t, row = qt*16 + quad*4 + reg
                #pragma unroll
                for (int r = 0; r < 4; ++r) {
                    const int qo = qt * 16 + quad * 4 + r;
                    y1s[tl][(qo * 32 + p) ^ xsw] = (unsigned short)f2bf(acc[r]);
                }
            }
        }
    }
    __syncthreads();

    // ---------- stage 2: per q: D[r][t] = R[q] (r x p) * Y1_q (p x t); y2 -> xs region ----------
    {
        const int xsw = 2 * tl;
        #pragma unroll
        for (int qq = 0; qq < 8; ++qq) {
            const int q = w * 8 + qq;             // waves partition q
            short8 b2;
            #pragma unroll
            for (int j = 0; j < 8; ++j)
                b2[j] = (short)y1s[tl][(q * 32 + quad * 8 + j) ^ xsw];
            #pragma unroll
            for (int rt = 0; rt < 2; ++rt) {
                const int r = rt * 16 + tl;
                const float* rp = R + ((q * 32 + r) * 32 + quad * 8);
                const float4 ra = *(const float4*)rp;
                const float4 rb = *(const float4*)(rp + 4);
                short8 a2;
                a2[0] = (short)f2bf(ra.x); a2[1] = (short)f2bf(ra.y);
                a2[2] = (short)f2bf(ra.z); a2[3] = (short)f2bf(ra.w);
                a2[4] = (short)f2bf(rb.x); a2[5] = (short)f2bf(rb.y);
                a2[6] = (short)f2bf(rb.z); a2[7] = (short)f2bf(rb.w);
                floatx4 acc = {0.f, 0.f, 0.f, 0.f};
                acc = __builtin_amdgcn_mfma_f32_16x16x32_bf16(a2, b2, acc, 0, 0, 0);
                #pragma unroll
                for (int r4 = 0; r4 < 4; ++r4) {
                    const int ro = rt * 16 + quad * 4 + r4;
                    xs[tl][(ro * 32 + q) ^ xsw] = (unsigned short)f2bf(acc[r4]);
                }
            }
        }
    }
    __syncthreads();

    // ---------- dump: y2 (in xs region) -> out, coalesced float4 ----------
    {
        const int c = tid * 4;
        #pragma unroll
        for (int t = 0; t < 16; ++t) {
            const unsigned int u0 = *(const unsigned int*)&xs[t][(c    ) ^ (2 * t)];
            const unsigned int u1 = *(const unsigned int*)&xs[t][(c + 2) ^ (2 * t)];
            float4 o;
            o.x = bf2f(u0 & 0xffffu); o.y = bf2f(u0 >> 16);
            o.z = bf2f(u1 & 0xffffu); o.w = bf2f(u1 >> 16);
            *(float4*)(out + (tok0 + t) * 1024 + c) = o;
        }
    }
}

extern "C" void kernel_launch(void* const* d_in, const int* in_sizes, int n_in,
                              void* d_out, int out_size, void* d_ws, size_t ws_size,
                              hipStream_t stream) {
    const float* x = (const float*)d_in[0];   // (8, 4096, 1024) fp32 -> 32768 tokens x 1024
    const float* L = (const float*)d_in[1];   // (32, 32, 32) fp32
    const float* R = (const float*)d_in[2];   // (32, 32, 32) fp32
    float* out = (float*)d_out;               // 32768 x 1024 fp32

    const int n_tokens = 8 * 4096;
    const int grid = n_tokens / 16;           // 2048 blocks, 16 tokens each
    monarch_kernel<<<grid, 256, 0, stream>>>(x, L, R, out);
}

// Round 2
// 242.131 us; speedup vs baseline: 1.1609x; 1.1609x over previous
//
#include <hip/hip_runtime.h>
#include <hip/hip_bf16.h>

// MonarchOutProjection: out[t][r*32+q] = sum_p R[q][r][p] * sum_m L[p][q][m] * x[t][m*32+p]
// Round 2: latency-bound fix.
//  - prep_weights pre-converts L/R -> bf16 MFMA A-fragments in d_ws (one dwordx4 per frag).
//  - single 32 KiB LDS buffer: stage1 transforms in place (per wave, read cols == write cols,
//    DS ops are in-order per wave); stage2 holds results in 64 VGPRs across the barrier.
//  -> 4 blocks/CU (LDS 32K, VGPR <=128), 16 waves/CU, 2x occupancy of round 1.

typedef __attribute__((ext_vector_type(8))) short short8;
typedef __attribute__((ext_vector_type(4))) float floatx4;

__device__ __forceinline__ unsigned int f2bf(float f) {
    unsigned int u = __float_as_uint(f);
    return (u + 0x7fffu + ((u >> 16) & 1u)) >> 16;   // RNE f32->bf16 bits
}
__device__ __forceinline__ unsigned int pack2bf(float a, float b) {
    __hip_bfloat162 h = __float22bfloat162_rn(float2{a, b});  // packed cvt where available
    return *(unsigned int*)&h;
}
__device__ __forceinline__ float bf2f(unsigned int u16) {
    return __uint_as_float(u16 << 16);
}

// Lb[(p*2+qt)*64 + lane] (short8) = L[p][q=qt*16+(lane&15)][m=(lane>>4)*8 .. +8] as bf16.
// Same for Rb. 8192 threads, one short8 each.
__global__ void prep_weights(const float* __restrict__ L, const float* __restrict__ R,
                             unsigned short* __restrict__ Lb, unsigned short* __restrict__ Rb) {
    const int t = blockIdx.x * 256 + threadIdx.x;          // 0..8191
    const float* src        = (t < 4096) ? L : R;
    unsigned short* dst     = (t < 4096) ? Lb : Rb;
    const int i    = t & 4095;                             // (p*2+qt)*64 + lane
    const int lane = i & 63;
    const int pq   = i >> 6;
    const int p    = pq >> 1;
    const int qt   = pq & 1;
    const int q    = qt * 16 + (lane & 15);
    const int m0   = (lane >> 4) * 8;
    const float* s = src + (p * 32 + q) * 32 + m0;
    uint4 o;
    o.x = pack2bf(s[0], s[1]);
    o.y = pack2bf(s[2], s[3]);
    o.z = pack2bf(s[4], s[5]);
    o.w = pack2bf(s[6], s[7]);
    *(uint4*)(dst + (size_t)i * 8) = o;
}

__global__ __launch_bounds__(256, 4)
void monarch_kernel(const float* __restrict__ x,
                    const unsigned short* __restrict__ Lb,
                    const unsigned short* __restrict__ Rb,
                    float* __restrict__ out) {
    // Element (t, c) lives at buf[t][c ^ (2*t)]; XOR touches bits 1..4 only, so
    // (32k + p) ^ 2t = 32k + (p ^ 2t): the swizzle permutes within each 32-col group
    // and u32 pairs stay contiguous. 16-bank spread -> 4-way conflicts (measured OK).
    __shared__ __align__(16) unsigned short buf[16][1024];   // 32 KiB

    const int tid  = threadIdx.x;
    const int w    = tid >> 6;
    const int lane = tid & 63;
    const int tl   = lane & 15;       // token row / MFMA col
    const int quad = lane >> 4;
    const long tok0 = (long)blockIdx.x * 16;

    // ---------- stage in: x tile -> buf (bf16, swizzled), coalesced float4 ----------
    {
        const int c = tid * 4;
        #pragma unroll
        for (int t = 0; t < 16; ++t) {
            const float4 v = *(const float4*)(x + (tok0 + t) * 1024 + c);
            *(unsigned int*)&buf[t][(c    ) ^ (2 * t)] = pack2bf(v.x, v.y);
            *(unsigned int*)&buf[t][(c + 2) ^ (2 * t)] = pack2bf(v.z, v.w);
        }
    }
    __syncthreads();

    // ---------- stage 1, IN PLACE: per p (wave-partitioned): D[q][t] = L[p] * X_p ----------
    // Wave reads cols {m*32 + (p^2tl)} (all m) then writes cols {q*32 + (p^2tl)} (all q):
    // identical column set, reads precede writes in the wave's instr stream, DS is in-order.
    {
        const int xsw = 2 * tl;
        #pragma unroll
        for (int pp = 0; pp < 8; ++pp) {
            const int p  = w * 8 + pp;
            const int pX = p ^ xsw;
            short8 b1;
            #pragma unroll
            for (int j = 0; j < 8; ++j)
                b1[j] = (short)buf[tl][quad * 256 + j * 32 + pX];
            #pragma unroll
            for (int qt = 0; qt < 2; ++qt) {
                const short8 a1 = *(const short8*)(Lb + (size_t)((p * 2 + qt) * 64 + lane) * 8);
                floatx4 acc = {0.f, 0.f, 0.f, 0.f};
                acc = __builtin_amdgcn_mfma_f32_16x16x32_bf16(a1, b1, acc, 0, 0, 0);
                #pragma unroll
                for (int r = 0; r < 4; ++r) {
                    const int qo = qt * 16 + quad * 4 + r;
                    buf[tl][qo * 32 + pX] = (unsigned short)f2bf(acc[r]);
                }
            }
        }
    }
    __syncthreads();

    // ---------- stage 2: per q (wave-partitioned): D[r][t] = R[q] * Y1_q ----------
    // Accumulate in registers; cannot write LDS until every wave's y1 reads are done.
    floatx4 acc2[8][2];
    {
        const int xsw = 2 * tl;
        #pragma unroll
        for (int qq = 0; qq < 8; ++qq) {
            const int q = w * 8 + qq;
            short8 b2;
            #pragma unroll
            for (int j = 0; j < 8; ++j)
                b2[j] = (short)buf[tl][q * 32 + ((quad * 8 + j) ^ xsw)];
            #pragma unroll
            for (int rt = 0; rt < 2; ++rt) {
                const short8 a2 = *(const short8*)(Rb + (size_t)((q * 2 + rt) * 64 + lane) * 8);
                floatx4 z = {0.f, 0.f, 0.f, 0.f};
                acc2[qq][rt] = __builtin_amdgcn_mfma_f32_16x16x32_bf16(a2, b2, z, 0, 0, 0);
            }
        }
    }
    __syncthreads();

    // ---------- y2 -> buf ----------
    {
        const int xsw = 2 * tl;
        #pragma unroll
        for (int qq = 0; qq < 8; ++qq) {
            const int q  = w * 8 + qq;
            const int qX = q ^ xsw;
            #pragma unroll
            for (int rt = 0; rt < 2; ++rt) {
                #pragma unroll
                for (int r4 = 0; r4 < 4; ++r4) {
                    const int ro = rt * 16 + quad * 4 + r4;
                    buf[tl][ro * 32 + qX] = (unsigned short)f2bf(acc2[qq][rt][r4]);
                }
            }
        }
    }
    __syncthreads();

    // ---------- dump: buf -> out, coalesced float4 ----------
    {
        const int c = tid * 4;
        #pragma unroll
        for (int t = 0; t < 16; ++t) {
            const unsigned int u0 = *(const unsigned int*)&buf[t][(c    ) ^ (2 * t)];
            const unsigned int u1 = *(const unsigned int*)&buf[t][(c + 2) ^ (2 * t)];
            float4 o;
            o.x = bf2f(u0 & 0xffffu); o.y = bf2f(u0 >> 16);
            o.z = bf2f(u1 & 0xffffu); o.w = bf2f(u1 >> 16);
            *(float4*)(out + (tok0 + t) * 1024 + c) = o;
        }
    }
}

extern "C" void kernel_launch(void* const* d_in, const int* in_sizes, int n_in,
                              void* d_out, int out_size, void* d_ws, size_t ws_size,
                              hipStream_t stream) {
    const float* x = (const float*)d_in[0];   // (8, 4096, 1024) fp32
    const float* L = (const float*)d_in[1];   // (32, 32, 32) fp32
    const float* R = (const float*)d_in[2];   // (32, 32, 32) fp32
    float* out = (float*)d_out;

    unsigned short* Lb = (unsigned short*)d_ws;          // 32768 bf16 = 64 KiB
    unsigned short* Rb = Lb + 32768;                     // 32768 bf16 = 64 KiB

    prep_weights<<<32, 256, 0, stream>>>(L, R, Lb, Rb);  // ~2 us, L2-resident after

    const int n_tokens = 8 * 4096;
    const int grid = n_tokens / 16;                      // 2048 blocks x 16 tokens
    monarch_kernel<<<grid, 256, 0, stream>>>(x, Lb, Rb, out);
}